// Round 9
// baseline (28.734 us; speedup 1.0000x reference)
//
#include <hip/hip_runtime.h>
#include <math.h>
#include <stdint.h>

// Problem dims (fixed): B=8, C=128, M=16, H=W=128
#define NB 8
#define NC 128
#define NM 16
#define HW (128*128)        // 16384 positions
#define NOUTM 15
#define CH 8                // channels per block
#define NCT (NC / CH)       // 16 channel tiles
#define PCHUNK 4            // -> grid 4*16*8 = 512 blocks = exactly 2/CU
#define F4C (HW / PCHUNK / 4)   // 1024 float4-groups per chunk -> 4 iters
#define NINF_PK 0xFC00FC00u // packed f16 {-inf,-inf}

__device__ __forceinline__ uint32_t pkmax(uint32_t a, uint32_t b) {
    uint32_t d;
    asm("v_pk_max_f16 %0, %1, %2" : "=v"(d) : "v"(a), "v"(b));
    return d;
}
__device__ __forceinline__ uint32_t bfi(uint32_t s, uint32_t a, uint32_t b) {
    uint32_t d;
    asm("v_bfi_b32 %0, %1, %2, %3" : "=v"(d) : "v"(s), "v"(a), "v"(b));
    return d;
}
__device__ __forceinline__ uint32_t cvt_dup(float f) {
    auto h = __builtin_amdgcn_cvt_pkrtz(f, f);   // monotone RTZ f32->f16 x2
    return __builtin_bit_cast(uint32_t, h);
}
__device__ __forceinline__ float h2f(uint32_t h16) {
    unsigned short u = (unsigned short)h16;
    __fp16 h = __builtin_bit_cast(__fp16, u);
    return (float)h;
}
// Exact f32 atomic max via CAS (values only grow from -inf).
__device__ __forceinline__ void atomicMaxF(float* addr, float val) {
    int* ia = (int*)addr;
    int cur = __float_as_int(-INFINITY);
    while (__int_as_float(cur) < val) {
        int prev = atomicCAS(ia, cur, __float_as_int(val));
        if (prev == cur) break;
        cur = prev;
    }
}

// ---------------------------------------------------------------------------
// Kernel 1: pack 15 mask planes into a bitmask per (b,pos).
// int4 loads; planes split 4-way across thread groups (4/4/4/3), partial
// bitmasks OR-combined through LDS.  Also inits out[] to -inf (stream-
// ordered before kernel 2; re-runs every replay -> deterministic).
// ---------------------------------------------------------------------------
__global__ __launch_bounds__(256) void pack_masks_k(
        const int* __restrict__ masks, uint32_t* __restrict__ packed,
        float* __restrict__ out) {
    int t    = threadIdx.x;
    int gid  = blockIdx.x * 64 + (t & 63);   // int4-group id, 0..32767
    int pset = t >> 6;                        // 0..3 -> planes 4/4/4/3
    int b    = gid >> 12;                     // 4096 groups per batch
    int p4   = gid & 4095;
    const int* mb = masks + (size_t)b * NM * HW + (size_t)p4 * 4;

    uint32_t b0 = 0, b1 = 0, b2 = 0, b3 = 0;
    int mlo = pset * 4 + 1;
    int mhi = (pset == 3) ? 15 : (mlo + 3);   // inclusive
    #pragma unroll
    for (int m = 1; m < NM; ++m) {
        if (m >= mlo && m <= mhi) {
            int4 mm = *(const int4*)(mb + (size_t)m * HW);
            int sh = m - 1;
            b0 |= ((uint32_t)mm.x) << sh;     // mask values are 0/1
            b1 |= ((uint32_t)mm.y) << sh;
            b2 |= ((uint32_t)mm.z) << sh;
            b3 |= ((uint32_t)mm.w) << sh;
        }
    }

    __shared__ uint4 lds[4][64];
    lds[pset][t & 63] = make_uint4(b0, b1, b2, b3);
    __syncthreads();
    if (t < 64) {
        uint4 a = lds[0][t], c = lds[1][t], d = lds[2][t], e = lds[3][t];
        uint4 r = make_uint4(a.x | c.x | d.x | e.x,
                             a.y | c.y | d.y | e.y,
                             a.z | c.z | d.z | e.z,
                             a.w | c.w | d.w | e.w);
        *(uint4*)(packed + (size_t)gid * 4) = r;
    }

    int flat = blockIdx.x * 256 + t;
    if (flat < NB * NC * NOUTM) out[flat] = -INFINITY;
}

// ---------------------------------------------------------------------------
// Kernel 2: block=(chunk,ctile,b); 8 channels x 4096 positions; 4 iters.
// EXPLICIT 2-deep software pipeline (A/B register buffers, constant-index
// arrays -> registers): next iteration's 9 x 16B loads stay in flight while
// the current iteration's ~640 VALU ops run.  launch_bounds(256,2): 256-VGPR
// budget holds acc[64] + both buffers.  Packed-f16 acc, perm+bfi, pk_max;
// 4-round LDS transpose reduce (17-pad); f32 CAS atomic-max into out.
// ---------------------------------------------------------------------------
#define DO_POS(BW, P, C)                                                      \
    {                                                                         \
        uint32_t vv[8] = {cvt_dup(P[0].C), cvt_dup(P[1].C), cvt_dup(P[2].C),  \
                          cvt_dup(P[3].C), cvt_dup(P[4].C), cvt_dup(P[5].C),  \
                          cvt_dup(P[6].C), cvt_dup(P[7].C)};                  \
        uint32_t bw_ = (BW);                                                  \
        _Pragma("unroll") for (int mp = 0; mp < 8; ++mp) {                    \
            uint32_t lo = (uint32_t)((int32_t)(bw_ << (31 - 2 * mp)) >> 31);  \
            uint32_t hi = (uint32_t)((int32_t)(bw_ << (30 - 2 * mp)) >> 31);  \
            uint32_t s01 = __builtin_amdgcn_perm(hi, lo, 0x05040100u);        \
            _Pragma("unroll") for (int ch = 0; ch < 8; ++ch) {                \
                acc[ch * 8 + mp] =                                            \
                    pkmax(acc[ch * 8 + mp], bfi(s01, vv[ch], NINF_PK));       \
            }                                                                 \
        }                                                                     \
    }

#define LOADG(P, BB, G)                                                       \
    {                                                                         \
        int i_ = (G) * 256 + t;                                               \
        BB = bits4[i_];                                                       \
        _Pragma("unroll") for (int q = 0; q < 8; ++q)                         \
            P[q] = e4[i_ + q * (HW / 4)];                                     \
    }

#define CRUNCH(P, BB)                                                         \
    DO_POS(BB.x, P, x) DO_POS(BB.y, P, y) DO_POS(BB.z, P, z) DO_POS(BB.w, P, w)

__global__ __launch_bounds__(256, 2) void region_partial_k(
        const float* __restrict__ encoded,
        const uint32_t* __restrict__ packed,
        float* __restrict__ out) {
    int chunk = blockIdx.x;            // 0..PCHUNK-1
    int ctile = blockIdx.y;            // 0..NCT-1
    int b     = blockIdx.z;            // 0..NB-1
    int t     = threadIdx.x;

    const uint4*  bits4 = (const uint4*)(packed + (size_t)b * HW)
                          + (size_t)chunk * F4C;
    const float4* e4    = (const float4*)(encoded
                          + ((size_t)b * NC + (size_t)ctile * CH) * HW)
                          + (size_t)chunk * F4C;

    uint32_t acc[64];
    #pragma unroll
    for (int w = 0; w < 64; ++w) acc[w] = NINF_PK;

    float4 A[8], B[8];
    uint4 Abb, Bbb;

    LOADG(A, Abb, 0)
    LOADG(B, Bbb, 1)
    CRUNCH(A, Abb)          // iter 0 (iter-1 loads in flight)
    LOADG(A, Abb, 2)
    CRUNCH(B, Bbb)          // iter 1 (iter-2 loads in flight)
    LOADG(B, Bbb, 3)
    CRUNCH(A, Abb)          // iter 2 (iter-3 loads in flight)
    CRUNCH(B, Bbb)          // iter 3

    // ---- 4-round x 16-word LDS transpose reduce (17-pad: conflict-free) ----
    __shared__ uint32_t ldsT[256 * 17];    // 17.4 KB (x2 blocks/CU = 35 KB)
    __shared__ uint32_t lds2[256];
    __shared__ uint32_t finalw[64];

    #pragma unroll
    for (int r = 0; r < 4; ++r) {
        if (r) __syncthreads();
        #pragma unroll
        for (int j = 0; j < 16; ++j) ldsT[t * 17 + j] = acc[r * 16 + j];
        __syncthreads();
        int w = t & 15, s = t >> 4;        // 16 segments of 16 rows
        uint32_t v = ldsT[(s * 16) * 17 + w];
        #pragma unroll
        for (int k = 1; k < 16; ++k)
            v = pkmax(v, ldsT[(s * 16 + k) * 17 + w]);
        lds2[s * 16 + w] = v;
        __syncthreads();
        if (t < 16) {
            uint32_t rr = lds2[t];
            #pragma unroll
            for (int k = 1; k < 16; ++k) rr = pkmax(rr, lds2[k * 16 + t]);
            finalw[r * 16 + t] = rr;       // global word index = ch*8 + mp
        }
    }
    __syncthreads();

    // 120 valid outputs: ch in [0,8), m in [0,15)
    if (t < CH * NOUTM) {
        int ch = t / NOUTM, m = t % NOUTM;
        uint32_t wv = finalw[ch * 8 + (m >> 1)];
        float f = h2f((m & 1) ? (wv >> 16) : (wv & 0xFFFFu));
        int c = ctile * CH + ch;
        atomicMaxF(out + ((size_t)b * NC + c) * NOUTM + m, f);
    }
}

extern "C" void kernel_launch(void* const* d_in, const int* in_sizes, int n_in,
                              void* d_out, int out_size, void* d_ws, size_t ws_size,
                              hipStream_t stream) {
    const float* encoded = (const float*)d_in[0];   // [8,128,128,128] f32
    const int*   masks   = (const int*)d_in[1];     // [8,16,128,128] i32
    float*       out     = (float*)d_out;           // [8,128,15,1] f32

    uint32_t* packed = (uint32_t*)d_ws;             // 512 KB

    pack_masks_k<<<512, 256, 0, stream>>>(masks, packed, out);

    dim3 grid2(PCHUNK, NCT, NB);   // 4 x 16 x 8 = 512 blocks = 2/CU, no tail
    region_partial_k<<<grid2, 256, 0, stream>>>(encoded, packed, out);
}